// Round 1
// baseline (323.474 us; speedup 1.0000x reference)
//
#include <hip/hip_runtime.h>
#include <hip/hip_bf16.h>
#include <stdint.h>

#define DEVFN static __device__ __forceinline__

typedef __attribute__((ext_vector_type(8))) short bf16x8;
typedef __attribute__((ext_vector_type(4))) short s16x4;
typedef __attribute__((ext_vector_type(4))) float f32x4;

static constexpr int TOK = 8192;       // B*N
static constexpr int DIM = 768;
static constexpr int HEADS = 8;
static constexpr int HD = 96;
static constexpr int EXPERTS = 24;
static constexpr int NQ = 2304;        // EXPERTS*HD
static constexpr int NQP = 2560;       // NQ + 192 (kv) + 64 (zero pad) -> mult of 128
static constexpr float ATT_SCALE = 0.10206207261596575f;  // 96^-0.5

// ---- workspace layout (bytes, all 256-aligned) ----
static constexpr size_t OFF_XB   = 0;          // x bf16 [8192][768]            12,582,912  (o aliases after GEMM1)
static constexpr size_t OFF_BT1  = 12582912;   // Bt1 bf16 [2560][768]           3,932,160
static constexpr size_t OFF_W2T  = 16515072;   // W2t bf16 [768][2304]           3,538,944
static constexpr size_t OFF_K    = 20054016;   // k bf16 [8192][96]              1,572,864
static constexpr size_t OFF_VT   = 21626880;   // vT bf16 [8][96][1024]          1,572,864
static constexpr size_t OFF_GATE = 23199744;   // gates f32 [8192][8]              262,144
static constexpr size_t OFF_TOPI = 23461888;   // topi i32 [8192][8]               262,144
static constexpr size_t OFF_AUX  = 23724032;   // me[24], fe[24], z              256
static constexpr size_t OFF_ALLQ = 23724288;   // allq bf16 [8192][2560]        41,943,040 (mixed aliases)
// total 65,667,328 bytes

DEVFN short f2bf(float f){
  __hip_bfloat16 h = __float2bfloat16(f);
  return __builtin_bit_cast(short, h);
}
DEVFN float bf2f(short u){
  return __bfloat162float(__builtin_bit_cast(__hip_bfloat16, u));
}

DEVFN void gload16(const void* g, void* l){
  auto gp = reinterpret_cast<__attribute__((address_space(1))) unsigned int*>(
      reinterpret_cast<uintptr_t>(g));
  auto lp = reinterpret_cast<__attribute__((address_space(3))) unsigned int*>(
      reinterpret_cast<uintptr_t>(l));
  __builtin_amdgcn_global_load_lds(gp, lp, 16, 0, 0);
}

// ---------------- casts / transposes ----------------
__global__ __launch_bounds__(256) void cast_x_kernel(const float4* __restrict__ x,
                                                     short* __restrict__ xb){
  int i = blockIdx.x*256 + threadIdx.x;          // 1,572,864 float4s exactly
  float4 v = x[i];
  s16x4 o4;
  o4[0] = f2bf(v.x); o4[1] = f2bf(v.y); o4[2] = f2bf(v.z); o4[3] = f2bf(v.w);
  *reinterpret_cast<s16x4*>(xb + (size_t)i*4) = o4;
}

__global__ __launch_bounds__(256) void build_bt1_w1(const float* __restrict__ W1,
                                                    short* __restrict__ Bt1){
  int i = blockIdx.x*256 + threadIdx.x;          // 24*768*96 exactly
  int e = i / (DIM*HD);
  int rem = i - e*(DIM*HD);
  int d = rem / HD, hh = rem - d*HD;
  Bt1[(size_t)(e*HD + hh)*DIM + d] = f2bf(W1[i]);   // Bt1[n][k] = W1[e][d][h]
}
__global__ __launch_bounds__(256) void build_bt1_kv(const float* __restrict__ Wkv,
                                                    short* __restrict__ Bt1){
  int i = blockIdx.x*256 + threadIdx.x;          // 768*192 exactly
  int d = i / 192, j = i - d*192;
  Bt1[(size_t)(NQ + j)*DIM + d] = f2bf(Wkv[i]);
}
__global__ __launch_bounds__(256) void build_bt1_pad(short* __restrict__ Bt1){
  int i = blockIdx.x*256 + threadIdx.x;          // 64*768 exactly
  Bt1[(size_t)(NQ + 192)*DIM + i] = 0;
}
__global__ __launch_bounds__(256) void build_w2t(const float* __restrict__ W2,
                                                 short* __restrict__ W2t){
  int i = blockIdx.x*256 + threadIdx.x;          // 24*96*768 exactly
  int e = i / (HD*DIM);
  int rem = i - e*(HD*DIM);
  int hh = rem / DIM, c = rem - hh*DIM;
  W2t[(size_t)c*NQ + e*HD + hh] = f2bf(W2[i]);      // W2t[c][e*96+h] = W2[e][h][c]
}

// ---------------- gating + aux ----------------
__global__ __launch_bounds__(256) void gating_kernel(const float* __restrict__ x,
                                                     const float* __restrict__ Wg,
                                                     const int* __restrict__ task,
                                                     int* __restrict__ topi,
                                                     float* __restrict__ gates,
                                                     float* __restrict__ auxbuf){
  __shared__ float lme[EXPERTS];
  __shared__ float lfr[EXPERTS];
  __shared__ float lz;
  int tid = threadIdx.x;
  if (tid < EXPERTS){ lme[tid] = 0.f; lfr[tid] = 0.f; }
  if (tid == 0) lz = 0.f;
  __syncthreads();

  int tk = tid >> 5, tl = tid & 31;              // 8 tokens/block, 32 lanes/token
  int token = blockIdx.x*8 + tk;
  const float* Wt = Wg + (size_t)task[0]*DIM*EXPERTS;
  const float* xr = x + (size_t)token*DIM;

  float acc[EXPERTS];
#pragma unroll
  for (int e=0;e<EXPERTS;++e) acc[e] = 0.f;
  for (int d = tl; d < DIM; d += 32){
    float xv = xr[d];
    const float* wr_ = Wt + d*EXPERTS;
#pragma unroll
    for (int e=0;e<EXPERTS;++e) acc[e] = fmaf(xv, wr_[e], acc[e]);
  }
#pragma unroll
  for (int e=0;e<EXPERTS;++e){
    float v = acc[e];
#pragma unroll
    for (int m=1;m<32;m<<=1) v += __shfl_xor(v, m, 64);
    acc[e] = v;
  }
  // f32 softmax (keeps top-k selection aligned with the reference)
  float mx = acc[0];
#pragma unroll
  for (int e=1;e<EXPERTS;++e) mx = fmaxf(mx, acc[e]);
  float p[EXPERTS]; float s = 0.f;
#pragma unroll
  for (int e=0;e<EXPERTS;++e){ p[e] = __expf(acc[e]-mx); s += p[e]; }
  float lse = mx + __logf(s);
  float inv = 1.f/s;
#pragma unroll
  for (int e=0;e<EXPERTS;++e) p[e] *= inv;
  // top-8 selection (strict > => lowest index wins ties, matches lax.top_k)
  unsigned selm = 0; float gsum = 0.f; int sel[8]; float sg[8];
#pragma unroll
  for (int t=0;t<8;++t){
    float best = -1.f; int bi = 0;
#pragma unroll
    for (int e=0;e<EXPERTS;++e){
      bool ok = !((selm>>e)&1u) && (p[e] > best);
      best = ok ? p[e] : best;
      bi   = ok ? e    : bi;
    }
    selm |= (1u<<bi); sel[t] = bi; sg[t] = best; gsum += best;
  }
  float dinv = 1.f/(gsum + 1e-6f);
  if (tl == 0){
#pragma unroll
    for (int t=0;t<8;++t){
      topi[token*HEADS + t]  = sel[t];
      gates[token*HEADS + t] = sg[t]*dinv;
    }
#pragma unroll
    for (int e=0;e<EXPERTS;++e) atomicAdd(&lme[e], p[e]);
#pragma unroll
    for (int t=0;t<8;++t) atomicAdd(&lfr[sel[t]], 1.f);
    atomicAdd(&lz, lse*lse);
  }
  __syncthreads();
  if (tid < EXPERTS) atomicAdd(&auxbuf[tid], lme[tid]);
  else if (tid >= 32 && tid < 32+EXPERTS) atomicAdd(&auxbuf[EXPERTS + tid-32], lfr[tid-32]);
  else if (tid == 63) atomicAdd(&auxbuf[2*EXPERTS], lz);
}

__global__ void aux_final(const float* __restrict__ auxbuf, float* __restrict__ outa){
  if (threadIdx.x != 0 || blockIdx.x != 0) return;
  float ms = 0.f, fs = 0.f;
  for (int e=0;e<EXPERTS;++e){ ms += auxbuf[e]; fs += auxbuf[EXPERTS+e]; }
  float sw = 0.f;
  for (int e=0;e<EXPERTS;++e) sw += (auxbuf[e]/ms)*(auxbuf[EXPERTS+e]/fs);
  sw *= (float)EXPERTS;
  float z = auxbuf[2*EXPERTS] / (float)TOK;
  outa[0] = 0.1f*sw + 0.001f*z;
}

// ---------------- bf16 MFMA GEMM: C[M,N] = A[M,K] * Bt[N,K]^T ----------------
// m97 structure: 128x128 tile, BK=64, 4 waves (2x2), global_load_lds(16B) staging.
template<bool OUT_BF16>
__global__ __launch_bounds__(256) void gemm_bt(const short* __restrict__ A,
                                               const short* __restrict__ Bt,
                                               void* __restrict__ Cout,
                                               int M, int N, int K){
  __shared__ short As[128*64];
  __shared__ short Bs[128*64];
  int tid = threadIdx.x;
  int lane = tid & 63, w = tid >> 6;
  int wr = w >> 1, wc = w & 1;
  int l15 = lane & 15, lg = lane >> 4;
  int m0 = blockIdx.y * 128, n0 = blockIdx.x * 128;

  f32x4 acc[4][4] = {};

  for (int k0 = 0; k0 < K; k0 += 64){
#pragma unroll
    for (int it = 0; it < 4; ++it){
      int c = it*256 + tid;                 // 1024 chunks of 16B per tile
      int row = c >> 3, cc = c & 7;
      gload16(A  + (size_t)(m0+row)*K + k0 + cc*8, (char*)As + (size_t)c*16);
      gload16(Bt + (size_t)(n0+row)*K + k0 + cc*8, (char*)Bs + (size_t)c*16);
    }
    __syncthreads();
#pragma unroll
    for (int kk = 0; kk < 2; ++kk){
      bf16x8 af[4], bfr[4];
#pragma unroll
      for (int m = 0; m < 4; ++m)
        af[m] = *reinterpret_cast<const bf16x8*>(&As[(wr*64 + m*16 + l15)*64 + kk*32 + lg*8]);
#pragma unroll
      for (int n = 0; n < 4; ++n)
        bfr[n] = *reinterpret_cast<const bf16x8*>(&Bs[(wc*64 + n*16 + l15)*64 + kk*32 + lg*8]);
#pragma unroll
      for (int m = 0; m < 4; ++m)
#pragma unroll
        for (int n = 0; n < 4; ++n)
          acc[m][n] = __builtin_amdgcn_mfma_f32_16x16x32_bf16(af[m], bfr[n], acc[m][n], 0, 0, 0);
    }
    __syncthreads();
  }
  // epilogue: D col=lane&15, row=(lane>>4)*4+reg  [m89-verified]
#pragma unroll
  for (int m = 0; m < 4; ++m)
#pragma unroll
    for (int n = 0; n < 4; ++n){
      int rbase = m0 + wr*64 + m*16 + lg*4;
      int col   = n0 + wc*64 + n*16 + l15;
#pragma unroll
      for (int r = 0; r < 4; ++r){
        float v = acc[m][n][r];
        size_t idx = (size_t)(rbase + r)*N + col;
        if constexpr (OUT_BF16) ((short*)Cout)[idx] = f2bf(v);
        else                    ((float*)Cout)[idx] = v;
      }
    }
}

// ---------------- split kv columns (+bias) out of allq ----------------
__global__ __launch_bounds__(256) void split_kv(const short* __restrict__ allq,
                                                const float* __restrict__ bkv,
                                                short* __restrict__ kbuf,
                                                short* __restrict__ vT){
  int token = blockIdx.x;
  int b = token >> 10, n = token & 1023;
  int t = threadIdx.x;
  if (t < HD){
    kbuf[(size_t)token*HD + t] = f2bf(bf2f(allq[(size_t)token*NQP + NQ + t]) + bkv[t]);
  } else if (t < 2*HD){
    int j = t - HD;
    vT[(size_t)b*HD*1024 + (size_t)j*1024 + n] =
        f2bf(bf2f(allq[(size_t)token*NQP + NQ + HD + j]) + bkv[HD + j]);
  }
}

// ---------------- flash attention, shared K/V across heads ----------------
__global__ __launch_bounds__(256) void attn_fwd(const short* __restrict__ allq,
                                                const int* __restrict__ topi,
                                                const short* __restrict__ kbuf,
                                                const short* __restrict__ vT,
                                                short* __restrict__ o){
  __shared__ short Klds[64*96];     // [key][hd]
  __shared__ short Vlds[96*64];     // [hd][key]
  __shared__ short Plds[4][16*64];  // per-wave P re-layout
  int qt = blockIdx.x;              // 16 q-tiles of 64 rows
  int bh = blockIdx.y;
  int b = bh >> 3, h = bh & 7;
  int tid = threadIdx.x;
  int lane = tid & 63, w = tid >> 6;
  int l15 = lane & 15, lg = lane >> 4;

  // gather this wave's Q fragments straight from allq via top_i
  int qrow = qt*64 + w*16 + l15;
  int token = b*1024 + qrow;
  int qe = topi[token*HEADS + h];
  const short* qp = allq + (size_t)token*NQP + qe*HD;
  bf16x8 qf[3];
#pragma unroll
  for (int t=0;t<3;++t) qf[t] = *reinterpret_cast<const bf16x8*>(qp + t*32 + lg*8);

  f32x4 Oacc[6] = {};
  float mrun[4], lrun[4];
#pragma unroll
  for (int r=0;r<4;++r){ mrun[r] = -3.0e38f; lrun[r] = 0.f; }

  const short* kb = kbuf + (size_t)b*1024*HD;
  const short* vb = vT  + (size_t)b*HD*1024;

  for (int n0 = 0; n0 < 1024; n0 += 64){
#pragma unroll
    for (int it = 0; it < 3; ++it){
      int c = it*256 + tid;                      // 768 chunks of 16B each
      gload16(kb + (size_t)n0*HD + c*8, (char*)Klds + (size_t)c*16);
      int vrow = c >> 3, vc = c & 7;
      gload16(vb + (size_t)vrow*1024 + n0 + vc*8, (char*)Vlds + (size_t)c*16);
    }
    __syncthreads();

    // S = Q K^T  (rows: this wave's 16 queries, cols: 64 keys)
    f32x4 sa[4];
#pragma unroll
    for (int ct=0;ct<4;++ct){
      f32x4 a = {};
#pragma unroll
      for (int t=0;t<3;++t){
        bf16x8 kf = *reinterpret_cast<const bf16x8*>(&Klds[(ct*16 + l15)*HD + t*32 + lg*8]);
        a = __builtin_amdgcn_mfma_f32_16x16x32_bf16(qf[t], kf, a, 0, 0, 0);
      }
      sa[ct] = a;
    }
#pragma unroll
    for (int ct=0;ct<4;++ct)
#pragma unroll
      for (int r=0;r<4;++r) sa[ct][r] *= ATT_SCALE;

    // online softmax; lane owns 4 rows (lg*4+r), 16-lane groups share rows
    float alpha[4];
#pragma unroll
    for (int r=0;r<4;++r){
      float mx = fmaxf(fmaxf(sa[0][r], sa[1][r]), fmaxf(sa[2][r], sa[3][r]));
#pragma unroll
      for (int d=1; d<16; d<<=1) mx = fmaxf(mx, __shfl_xor(mx, d, 64));
      float mnew = fmaxf(mrun[r], mx);
      alpha[r] = __expf(mrun[r] - mnew);
      float s = 0.f;
#pragma unroll
      for (int ct=0;ct<4;++ct){
        float pp = __expf(sa[ct][r] - mnew);
        sa[ct][r] = pp; s += pp;
      }
#pragma unroll
      for (int d=1; d<16; d<<=1) s += __shfl_xor(s, d, 64);
      lrun[r] = lrun[r]*alpha[r] + s;
      mrun[r] = mnew;
    }
#pragma unroll
    for (int dt=0;dt<6;++dt)
#pragma unroll
      for (int r=0;r<4;++r) Oacc[dt][r] *= alpha[r];

    // P: D-layout -> LDS -> A-fragment layout (wave-local, no barrier needed)
#pragma unroll
    for (int ct=0;ct<4;++ct)
#pragma unroll
      for (int r=0;r<4;++r)
        Plds[w][(lg*4 + r)*64 + ct*16 + l15] = f2bf(sa[ct][r]);

#pragma unroll
    for (int ks=0;ks<2;++ks){
      bf16x8 pa = *reinterpret_cast<const bf16x8*>(&Plds[w][l15*64 + ks*32 + lg*8]);
#pragma unroll
      for (int dt=0;dt<6;++dt){
        bf16x8 vf = *reinterpret_cast<const bf16x8*>(&Vlds[(dt*16 + l15)*64 + ks*32 + lg*8]);
        Oacc[dt] = __builtin_amdgcn_mfma_f32_16x16x32_bf16(pa, vf, Oacc[dt], 0, 0, 0);
      }
    }
    __syncthreads();
  }

  short* ob = o + ((size_t)(b*1024 + qt*64 + w*16))*HEADS*HD + (size_t)h*HD;
#pragma unroll
  for (int r=0;r<4;++r){
    float inv = 1.f / lrun[r];
#pragma unroll
    for (int dt=0;dt<6;++dt)
      ob[(size_t)(lg*4 + r)*HEADS*HD + dt*16 + l15] = f2bf(Oacc[dt][r]*inv);
  }
}

// ---------------- build dense mixed = one_hot(top_i)*gates applied to o ----------------
__global__ __launch_bounds__(256) void scatter_mixed(const short* __restrict__ o,
                                                     const int* __restrict__ topi,
                                                     const float* __restrict__ gates,
                                                     short* __restrict__ mixed){
  __shared__ int inv[EXPERTS];
  __shared__ float g[HEADS];
  int token = blockIdx.x;
  int tid = threadIdx.x;
  if (tid < EXPERTS) inv[tid] = -1;
  __syncthreads();
  if (tid < HEADS){
    inv[topi[token*HEADS + tid]] = tid;
    g[tid] = gates[token*HEADS + tid];
  }
  __syncthreads();
  for (int t = tid; t < NQ; t += 256){
    int e = t / HD, dd = t - e*HD;
    int hh = inv[e];
    float val = (hh >= 0) ? g[hh] * bf2f(o[(size_t)token*HEADS*HD + hh*HD + dd]) : 0.f;
    mixed[(size_t)token*NQ + t] = f2bf(val);
  }
}

// ---------------- launch ----------------
extern "C" void kernel_launch(void* const* d_in, const int* in_sizes, int n_in,
                              void* d_out, int out_size, void* d_ws, size_t ws_size,
                              hipStream_t stream) {
  (void)in_sizes; (void)n_in; (void)out_size; (void)ws_size;
  const float* x    = (const float*)d_in[0];
  const float* Wg   = (const float*)d_in[1];
  const float* W1   = (const float*)d_in[2];
  const float* W2   = (const float*)d_in[3];
  const float* Wkv  = (const float*)d_in[4];
  const float* bkv  = (const float*)d_in[5];
  const int*   task = (const int*)d_in[6];

  char* ws = (char*)d_ws;
  short* xb    = (short*)(ws + OFF_XB);
  short* o     = (short*)(ws + OFF_XB);    // alias: xb dead after GEMM1
  short* Bt1   = (short*)(ws + OFF_BT1);
  short* W2t   = (short*)(ws + OFF_W2T);
  short* kbuf  = (short*)(ws + OFF_K);
  short* vT    = (short*)(ws + OFF_VT);
  float* gates = (float*)(ws + OFF_GATE);
  int*   topi  = (int*)(ws + OFF_TOPI);
  float* aux   = (float*)(ws + OFF_AUX);
  short* allq  = (short*)(ws + OFF_ALLQ);
  short* mixed = (short*)(ws + OFF_ALLQ);  // alias: allq dead after attn q-gather
  float* out   = (float*)d_out;

  hipMemsetAsync(aux, 0, 256, stream);
  cast_x_kernel<<<6144, 256, 0, stream>>>((const float4*)x, xb);
  build_bt1_w1 <<<6912, 256, 0, stream>>>(W1, Bt1);
  build_bt1_kv <<<576,  256, 0, stream>>>(Wkv, Bt1);
  build_bt1_pad<<<192,  256, 0, stream>>>(Bt1);
  build_w2t    <<<6912, 256, 0, stream>>>(W2, W2t);
  gating_kernel<<<1024, 256, 0, stream>>>(x, Wg, task, topi, gates, aux);
  aux_final    <<<1, 64, 0, stream>>>(aux, out + (size_t)TOK*DIM);
  // all_q (+ kv columns): [8192,768] x [768,2560]
  gemm_bt<true><<<dim3(NQP/128, TOK/128), 256, 0, stream>>>(xb, Bt1, allq, TOK, NQP, DIM);
  split_kv     <<<TOK, 256, 0, stream>>>(allq, bkv, kbuf, vT);
  attn_fwd     <<<dim3(16, 64), 256, 0, stream>>>(allq, topi, kbuf, vT, o);
  scatter_mixed<<<TOK, 256, 0, stream>>>(o, topi, gates, mixed);
  // out: [8192,2304] x [2304,768]
  gemm_bt<false><<<dim3(DIM/128, TOK/128), 256, 0, stream>>>(mixed, W2t, out, TOK, DIM, NQ);
}

// Round 2
// 289.393 us; speedup vs baseline: 1.1178x; 1.1178x over previous
//
#include <hip/hip_runtime.h>
#include <hip/hip_bf16.h>
#include <stdint.h>

#define DEVFN static __device__ __forceinline__

typedef __attribute__((ext_vector_type(8))) short bf16x8;
typedef __attribute__((ext_vector_type(4))) short s16x4;
typedef __attribute__((ext_vector_type(4))) float f32x4;

static constexpr int TOK = 8192;       // B*N
static constexpr int DIM = 768;
static constexpr int HEADS = 8;
static constexpr int HD = 96;
static constexpr int EXPERTS = 24;
static constexpr int NQ = 2304;        // EXPERTS*HD
static constexpr int NQP = 2560;       // NQ + 192 (kv) + 64 (zero pad)
static constexpr float C2 = 0.14724484f;   // HD^-0.5 * log2(e)
static constexpr float THRRAW = 78.0f;     // defer-max threshold in raw-score units (8/SCALE)

// ---- workspace layout (bytes) ----
static constexpr size_t OFF_XB   = 0;          // x bf16 [8192][768]   (o aliases)
static constexpr size_t OFF_BT1  = 12582912;   // Bt1 bf16 [2560][768]
static constexpr size_t OFF_W2T  = 16515072;   // W2t bf16 [768][2304]
static constexpr size_t OFF_K    = 20054016;   // Kp packed bf16 [128 tiles][12][64][8]
static constexpr size_t OFF_VT   = 21626880;   // Vp packed bf16 [128 tiles][8][96][8]
static constexpr size_t OFF_GATE = 23199744;   // gates f32 [8192][8]
static constexpr size_t OFF_TOPI = 23461888;   // topi i32 [8192][8]
static constexpr size_t OFF_AUX  = 23724032;   // me[24], fe[24], z
static constexpr size_t OFF_ALLQ = 23724288;   // allq bf16 [8192][2560] (mixed aliases)

DEVFN short f2bf(float f){
  __hip_bfloat16 h = __float2bfloat16(f);
  return __builtin_bit_cast(short, h);
}
DEVFN float bf2f(short u){
  return __bfloat162float(__builtin_bit_cast(__hip_bfloat16, u));
}

DEVFN void gload16(const void* g, void* l){
  auto gp = reinterpret_cast<__attribute__((address_space(1))) unsigned int*>(
      reinterpret_cast<uintptr_t>(g));
  auto lp = reinterpret_cast<__attribute__((address_space(3))) unsigned int*>(
      reinterpret_cast<uintptr_t>(l));
  __builtin_amdgcn_global_load_lds(gp, lp, 16, 0, 0);
}

// ---------------- fused prep: casts / transposes ----------------
__global__ __launch_bounds__(256) void prep_kernel(const float* __restrict__ x,
                                                   const float* __restrict__ W1,
                                                   const float* __restrict__ Wkv,
                                                   const float* __restrict__ W2,
                                                   short* __restrict__ xb,
                                                   short* __restrict__ Bt1,
                                                   short* __restrict__ W2t){
  int bid = blockIdx.x, tid = threadIdx.x;
  if (bid < 6144){                                    // cast x -> bf16
    int i = bid*256 + tid;
    float4 v = ((const float4*)x)[i];
    s16x4 o4;
    o4[0] = f2bf(v.x); o4[1] = f2bf(v.y); o4[2] = f2bf(v.z); o4[3] = f2bf(v.w);
    *reinterpret_cast<s16x4*>(xb + (size_t)i*4) = o4;
  } else if (bid < 13056){                            // W1 -> Bt1[n][k]
    int i = (bid-6144)*256 + tid;                     // 24*768*96
    int e = i / (DIM*HD);
    int rem = i - e*(DIM*HD);
    int d = rem / HD, hh = rem - d*HD;
    Bt1[(size_t)(e*HD + hh)*DIM + d] = f2bf(W1[i]);
  } else if (bid < 13632){                            // Wkv -> Bt1 kv rows
    int i = (bid-13056)*256 + tid;                    // 768*192
    int d = i / 192, j = i - d*192;
    Bt1[(size_t)(NQ + j)*DIM + d] = f2bf(Wkv[i]);
  } else if (bid < 13824){                            // zero pad rows
    int i = (bid-13632)*256 + tid;                    // 64*768
    Bt1[(size_t)(NQ + 192)*DIM + i] = 0;
  } else {                                            // W2 -> W2t[c][e*96+h]
    int i = (bid-13824)*256 + tid;                    // 24*96*768
    int e = i / (HD*DIM);
    int rem = i - e*(HD*DIM);
    int hh = rem / DIM, c = rem - hh*DIM;
    W2t[(size_t)c*NQ + e*HD + hh] = f2bf(W2[i]);
  }
}

// ---------------- gating + aux ----------------
__global__ __launch_bounds__(256) void gating_kernel(const float* __restrict__ x,
                                                     const float* __restrict__ Wg,
                                                     const int* __restrict__ task,
                                                     int* __restrict__ topi,
                                                     float* __restrict__ gates,
                                                     float* __restrict__ auxbuf){
  __shared__ float lme[EXPERTS];
  __shared__ float lfr[EXPERTS];
  __shared__ float lz;
  int tid = threadIdx.x;
  if (tid < EXPERTS){ lme[tid] = 0.f; lfr[tid] = 0.f; }
  if (tid == 0) lz = 0.f;
  __syncthreads();

  int tk = tid >> 5, tl = tid & 31;
  int token = blockIdx.x*8 + tk;
  const float* Wt = Wg + (size_t)task[0]*DIM*EXPERTS;
  const float* xr = x + (size_t)token*DIM;

  float acc[EXPERTS];
#pragma unroll
  for (int e=0;e<EXPERTS;++e) acc[e] = 0.f;
  for (int d = tl; d < DIM; d += 32){
    float xv = xr[d];
    const float* wr_ = Wt + d*EXPERTS;
#pragma unroll
    for (int e=0;e<EXPERTS;++e) acc[e] = fmaf(xv, wr_[e], acc[e]);
  }
#pragma unroll
  for (int e=0;e<EXPERTS;++e){
    float v = acc[e];
#pragma unroll
    for (int m=1;m<32;m<<=1) v += __shfl_xor(v, m, 64);
    acc[e] = v;
  }
  float mx = acc[0];
#pragma unroll
  for (int e=1;e<EXPERTS;++e) mx = fmaxf(mx, acc[e]);
  float p[EXPERTS]; float s = 0.f;
#pragma unroll
  for (int e=0;e<EXPERTS;++e){ p[e] = __expf(acc[e]-mx); s += p[e]; }
  float lse = mx + __logf(s);
  float inv = 1.f/s;
#pragma unroll
  for (int e=0;e<EXPERTS;++e) p[e] *= inv;
  unsigned selm = 0; float gsum = 0.f; int sel[8]; float sg[8];
#pragma unroll
  for (int t=0;t<8;++t){
    float best = -1.f; int bi = 0;
#pragma unroll
    for (int e=0;e<EXPERTS;++e){
      bool ok = !((selm>>e)&1u) && (p[e] > best);
      best = ok ? p[e] : best;
      bi   = ok ? e    : bi;
    }
    selm |= (1u<<bi); sel[t] = bi; sg[t] = best; gsum += best;
  }
  float dinv = 1.f/(gsum + 1e-6f);
  if (tl == 0){
#pragma unroll
    for (int t=0;t<8;++t){
      topi[token*HEADS + t]  = sel[t];
      gates[token*HEADS + t] = sg[t]*dinv;
    }
#pragma unroll
    for (int e=0;e<EXPERTS;++e) atomicAdd(&lme[e], p[e]);
#pragma unroll
    for (int t=0;t<8;++t) atomicAdd(&lfr[sel[t]], 1.f);
    atomicAdd(&lz, lse*lse);
  }
  __syncthreads();
  if (tid < EXPERTS) atomicAdd(&auxbuf[tid], lme[tid]);
  else if (tid >= 32 && tid < 32+EXPERTS) atomicAdd(&auxbuf[EXPERTS + tid-32], lfr[tid-32]);
  else if (tid == 63) atomicAdd(&auxbuf[2*EXPERTS], lz);
}

__global__ void aux_final(const float* __restrict__ auxbuf, float* __restrict__ outa){
  if (threadIdx.x != 0 || blockIdx.x != 0) return;
  float ms = 0.f, fs = 0.f;
  for (int e=0;e<EXPERTS;++e){ ms += auxbuf[e]; fs += auxbuf[EXPERTS+e]; }
  float sw = 0.f;
  for (int e=0;e<EXPERTS;++e) sw += (auxbuf[e]/ms)*(auxbuf[EXPERTS+e]/fs);
  sw *= (float)EXPERTS;
  float z = auxbuf[2*EXPERTS] / (float)TOK;
  outa[0] = 0.1f*sw + 0.001f*z;
}

// ---------------- bf16 MFMA GEMM: 128x128 tile, XCD-swizzled ----------------
template<bool OUT_BF16>
__global__ __launch_bounds__(256) void gemm_bt(const short* __restrict__ A,
                                               const short* __restrict__ Bt,
                                               void* __restrict__ Cout,
                                               int M, int N, int K){
  __shared__ short As[128*64];
  __shared__ short Bs[128*64];
  int nwg = gridDim.x*gridDim.y;
  int orig = blockIdx.y*gridDim.x + blockIdx.x;
  int cpx = nwg >> 3;
  int swz = (orig & 7)*cpx + (orig >> 3);   // requires nwg % 8 == 0
  int bx = swz % gridDim.x, by = swz / gridDim.x;

  int tid = threadIdx.x;
  int lane = tid & 63, w = tid >> 6;
  int wr = w >> 1, wc = w & 1;
  int l15 = lane & 15, lg = lane >> 4;
  int m0 = by * 128, n0 = bx * 128;

  f32x4 acc[4][4] = {};

  for (int k0 = 0; k0 < K; k0 += 64){
#pragma unroll
    for (int it = 0; it < 4; ++it){
      int c = it*256 + tid;
      int row = c >> 3, cc = c & 7;
      gload16(A  + (size_t)(m0+row)*K + k0 + cc*8, (char*)As + (size_t)c*16);
      gload16(Bt + (size_t)(n0+row)*K + k0 + cc*8, (char*)Bs + (size_t)c*16);
    }
    __syncthreads();
#pragma unroll
    for (int kk = 0; kk < 2; ++kk){
      bf16x8 af[4], bfr[4];
#pragma unroll
      for (int m = 0; m < 4; ++m)
        af[m] = *reinterpret_cast<const bf16x8*>(&As[(wr*64 + m*16 + l15)*64 + kk*32 + lg*8]);
#pragma unroll
      for (int n = 0; n < 4; ++n)
        bfr[n] = *reinterpret_cast<const bf16x8*>(&Bs[(wc*64 + n*16 + l15)*64 + kk*32 + lg*8]);
#pragma unroll
      for (int m = 0; m < 4; ++m)
#pragma unroll
        for (int n = 0; n < 4; ++n)
          acc[m][n] = __builtin_amdgcn_mfma_f32_16x16x32_bf16(af[m], bfr[n], acc[m][n], 0, 0, 0);
    }
    __syncthreads();
  }
#pragma unroll
  for (int m = 0; m < 4; ++m)
#pragma unroll
    for (int n = 0; n < 4; ++n){
      int rbase = m0 + wr*64 + m*16 + lg*4;
      int col   = n0 + wc*64 + n*16 + l15;
#pragma unroll
      for (int r = 0; r < 4; ++r){
        float v = acc[m][n][r];
        size_t idx = (size_t)(rbase + r)*N + col;
        if constexpr (OUT_BF16) ((short*)Cout)[idx] = f2bf(v);
        else                    ((float*)Cout)[idx] = v;
      }
    }
}

// ---------------- GEMM 128x64 tile (f32 out) for the reduce GEMM ----------------
__global__ __launch_bounds__(256) void gemm_bt_n64(const short* __restrict__ A,
                                                   const short* __restrict__ Bt,
                                                   float* __restrict__ Cout,
                                                   int M, int N, int K){
  __shared__ short As[128*64];
  __shared__ short Bs[64*64];
  int nwg = gridDim.x*gridDim.y;
  int orig = blockIdx.y*gridDim.x + blockIdx.x;
  int cpx = nwg >> 3;
  int swz = (orig & 7)*cpx + (orig >> 3);
  int bx = swz % gridDim.x, by = swz / gridDim.x;

  int tid = threadIdx.x;
  int lane = tid & 63, w = tid >> 6;
  int l15 = lane & 15, lg = lane >> 4;
  int m0 = by * 128, n0 = bx * 64;

  f32x4 acc[2][4] = {};

  for (int k0 = 0; k0 < K; k0 += 64){
#pragma unroll
    for (int it = 0; it < 4; ++it){
      int c = it*256 + tid;
      int row = c >> 3, cc = c & 7;
      gload16(A + (size_t)(m0+row)*K + k0 + cc*8, (char*)As + (size_t)c*16);
    }
#pragma unroll
    for (int it = 0; it < 2; ++it){
      int c = it*256 + tid;
      int row = c >> 3, cc = c & 7;
      gload16(Bt + (size_t)(n0+row)*K + k0 + cc*8, (char*)Bs + (size_t)c*16);
    }
    __syncthreads();
#pragma unroll
    for (int kk = 0; kk < 2; ++kk){
      bf16x8 af[2], bfr[4];
#pragma unroll
      for (int m = 0; m < 2; ++m)
        af[m] = *reinterpret_cast<const bf16x8*>(&As[(w*32 + m*16 + l15)*64 + kk*32 + lg*8]);
#pragma unroll
      for (int n = 0; n < 4; ++n)
        bfr[n] = *reinterpret_cast<const bf16x8*>(&Bs[(n*16 + l15)*64 + kk*32 + lg*8]);
#pragma unroll
      for (int m = 0; m < 2; ++m)
#pragma unroll
        for (int n = 0; n < 4; ++n)
          acc[m][n] = __builtin_amdgcn_mfma_f32_16x16x32_bf16(af[m], bfr[n], acc[m][n], 0, 0, 0);
    }
    __syncthreads();
  }
#pragma unroll
  for (int m = 0; m < 2; ++m)
#pragma unroll
    for (int n = 0; n < 4; ++n){
      int rbase = m0 + w*32 + m*16 + lg*4;
      int col   = n0 + n*16 + l15;
#pragma unroll
      for (int r = 0; r < 4; ++r)
        Cout[(size_t)(rbase + r)*N + col] = acc[m][n][r];
    }
}

// ---------------- split kv: bias + repack into fragment-chunk order ----------------
// Kp: per (b,tile): [kc(12)][key(64)] chunks of 8 hd-elems.
// Vp: per (b,tile): [kc(8, key-chunks)][hd(96)] chunks of 8 keys.
__global__ __launch_bounds__(256) void split_kv_tile(const short* __restrict__ allq,
                                                     const float* __restrict__ bkv,
                                                     short* __restrict__ Kp,
                                                     short* __restrict__ Vp){
  __shared__ short kv[64*192];
  int bt = blockIdx.x;                 // b*16 + nt
  int b = bt >> 4;
  int tid = threadIdx.x;
#pragma unroll
  for (int it = 0; it < 6; ++it){
    int c = it*256 + tid;              // 1536 chunks of 16B
    int j = c / 24, cc = c - j*24;
    int token = b*1024 + (bt & 15)*64 + j;
    gload16(allq + (size_t)token*NQP + NQ + cc*8, (char*)kv + (size_t)c*16);
  }
  __syncthreads();
#pragma unroll
  for (int it = 0; it < 3; ++it){
    int c = it*256 + tid;              // 768 K chunks
    int kc = c >> 6, j = c & 63;
    bf16x8 v = *reinterpret_cast<const bf16x8*>(&kv[j*192 + kc*8]);
    bf16x8 o8;
#pragma unroll
    for (int e = 0; e < 8; ++e) o8[e] = f2bf(bf2f(v[e]) + bkv[kc*8 + e]);
    *reinterpret_cast<bf16x8*>(Kp + ((size_t)bt*768 + c)*8) = o8;
  }
#pragma unroll
  for (int it = 0; it < 3; ++it){
    int c = it*256 + tid;              // 768 V chunks
    int kc = c / 96, hd = c - kc*96;
    float bias = bkv[96 + hd];
    bf16x8 o8;
#pragma unroll
    for (int e = 0; e < 8; ++e) o8[e] = f2bf(bf2f(kv[(kc*8 + e)*192 + 96 + hd]) + bias);
    *reinterpret_cast<bf16x8*>(Vp + ((size_t)bt*768 + c)*8) = o8;
  }
}

// ---------------- flash attention, conflict-free LDS, defer-max ----------------
__global__ __launch_bounds__(256) void attn_fwd(const short* __restrict__ allq,
                                                const int* __restrict__ topi,
                                                const short* __restrict__ Kp,
                                                const short* __restrict__ Vp,
                                                short* __restrict__ o){
  __shared__ short Klds[768*8];        // [kc12][key64] chunks
  __shared__ short Vlds[768*8];        // [kc8][hd96] chunks
  __shared__ short Plds[4][16*72];     // padded stride 72 -> 2-way max
  int qt = blockIdx.x, bh = blockIdx.y;
  int b = bh >> 3, h = bh & 7;
  int tid = threadIdx.x;
  int lane = tid & 63, w = tid >> 6;
  int l15 = lane & 15, lg = lane >> 4;

  int token = b*1024 + qt*64 + w*16 + l15;
  int qe = topi[token*HEADS + h];
  const short* qp = allq + (size_t)token*NQP + qe*HD;
  bf16x8 qf[3];
#pragma unroll
  for (int t=0;t<3;++t) qf[t] = *reinterpret_cast<const bf16x8*>(qp + t*32 + lg*8);

  f32x4 Oacc[6] = {};
  float mrun[4], lrun[4];
#pragma unroll
  for (int r=0;r<4;++r){ mrun[r] = -1.0e30f; lrun[r] = 0.f; }

  for (int nt = 0; nt < 16; ++nt){
    const short* kb = Kp + ((size_t)(b*16 + nt))*768*8;
    const short* vb = Vp + ((size_t)(b*16 + nt))*768*8;
#pragma unroll
    for (int it = 0; it < 3; ++it){
      int c = it*256 + tid;
      gload16(kb + (size_t)c*8, (char*)Klds + (size_t)c*16);
      gload16(vb + (size_t)c*8, (char*)Vlds + (size_t)c*16);
    }
    __syncthreads();

    // S = Q K^T (raw, unscaled)
    f32x4 sa[4];
    __builtin_amdgcn_s_setprio(1);
#pragma unroll
    for (int ct=0;ct<4;++ct){
      f32x4 a = {};
#pragma unroll
      for (int t=0;t<3;++t){
        bf16x8 kf = *reinterpret_cast<const bf16x8*>(&Klds[((t*4+lg)*64 + ct*16 + l15)*8]);
        a = __builtin_amdgcn_mfma_f32_16x16x32_bf16(qf[t], kf, a, 0, 0, 0);
      }
      sa[ct] = a;
    }
    __builtin_amdgcn_s_setprio(0);

    // row max (raw units)
    float mx[4];
#pragma unroll
    for (int r=0;r<4;++r)
      mx[r] = fmaxf(fmaxf(sa[0][r], sa[1][r]), fmaxf(sa[2][r], sa[3][r]));
#pragma unroll
    for (int d=1; d<16; d<<=1)
#pragma unroll
      for (int r=0;r<4;++r) mx[r] = fmaxf(mx[r], __shfl_xor(mx[r], d, 64));

    bool need = false;
#pragma unroll
    for (int r=0;r<4;++r) need = need || (mx[r] > mrun[r] + THRRAW);
    if (__any(need)){
#pragma unroll
      for (int r=0;r<4;++r){
        float mnew = fmaxf(mrun[r], mx[r]);
        float alpha = exp2f((mrun[r] - mnew)*C2);
        mrun[r] = mnew; lrun[r] *= alpha;
#pragma unroll
        for (int dt=0;dt<6;++dt) Oacc[dt][r] *= alpha;
      }
    }

    // P = exp2((S - m)*C2), row sums
    float s[4];
#pragma unroll
    for (int r=0;r<4;++r){
      float mc = mrun[r]*C2;
      float acc = 0.f;
#pragma unroll
      for (int ct=0;ct<4;++ct){
        float p = exp2f(fmaf(sa[ct][r], C2, -mc));
        sa[ct][r] = p; acc += p;
      }
      s[r] = acc;
    }
#pragma unroll
    for (int d=1; d<16; d<<=1)
#pragma unroll
      for (int r=0;r<4;++r) s[r] += __shfl_xor(s[r], d, 64);
#pragma unroll
    for (int r=0;r<4;++r) lrun[r] += s[r];

    // P: D-layout -> padded LDS -> A-fragment layout (wave-local)
#pragma unroll
    for (int ct=0;ct<4;++ct)
#pragma unroll
      for (int r=0;r<4;++r)
        Plds[w][(lg*4 + r)*72 + ct*16 + l15] = f2bf(sa[ct][r]);

    __builtin_amdgcn_s_setprio(1);
#pragma unroll
    for (int ks=0;ks<2;++ks){
      bf16x8 pa = *reinterpret_cast<const bf16x8*>(&Plds[w][l15*72 + ks*32 + lg*8]);
#pragma unroll
      for (int dt=0;dt<6;++dt){
        bf16x8 vf = *reinterpret_cast<const bf16x8*>(&Vlds[((ks*4+lg)*96 + dt*16 + l15)*8]);
        Oacc[dt] = __builtin_amdgcn_mfma_f32_16x16x32_bf16(pa, vf, Oacc[dt], 0, 0, 0);
      }
    }
    __builtin_amdgcn_s_setprio(0);
    __syncthreads();
  }

  short* ob = o + ((size_t)(b*1024 + qt*64 + w*16))*HEADS*HD + (size_t)h*HD;
#pragma unroll
  for (int r=0;r<4;++r){
    float inv = 1.f / lrun[r];
#pragma unroll
    for (int dt=0;dt<6;++dt)
      ob[(size_t)(lg*4 + r)*HEADS*HD + dt*16 + l15] = f2bf(Oacc[dt][r]*inv);
  }
}

// ---------------- build dense mixed ----------------
__global__ __launch_bounds__(256) void scatter_mixed(const short* __restrict__ o,
                                                     const int* __restrict__ topi,
                                                     const float* __restrict__ gates,
                                                     short* __restrict__ mixed){
  __shared__ int inv[EXPERTS];
  __shared__ float g[HEADS];
  int token = blockIdx.x;
  int tid = threadIdx.x;
  if (tid < EXPERTS) inv[tid] = -1;
  __syncthreads();
  if (tid < HEADS){
    inv[topi[token*HEADS + tid]] = tid;
    g[tid] = gates[token*HEADS + tid];
  }
  __syncthreads();
  for (int t = tid; t < NQ; t += 256){
    int e = t / HD, dd = t - e*HD;
    int hh = inv[e];
    float val = (hh >= 0) ? g[hh] * bf2f(o[(size_t)token*HEADS*HD + hh*HD + dd]) : 0.f;
    mixed[(size_t)token*NQ + t] = f2bf(val);
  }
}

// ---------------- launch ----------------
extern "C" void kernel_launch(void* const* d_in, const int* in_sizes, int n_in,
                              void* d_out, int out_size, void* d_ws, size_t ws_size,
                              hipStream_t stream) {
  (void)in_sizes; (void)n_in; (void)out_size; (void)ws_size;
  const float* x    = (const float*)d_in[0];
  const float* Wg   = (const float*)d_in[1];
  const float* W1   = (const float*)d_in[2];
  const float* W2   = (const float*)d_in[3];
  const float* Wkv  = (const float*)d_in[4];
  const float* bkv  = (const float*)d_in[5];
  const int*   task = (const int*)d_in[6];

  char* ws = (char*)d_ws;
  short* xb    = (short*)(ws + OFF_XB);
  short* o     = (short*)(ws + OFF_XB);    // alias: xb dead after GEMM1
  short* Bt1   = (short*)(ws + OFF_BT1);
  short* W2t   = (short*)(ws + OFF_W2T);
  short* Kp    = (short*)(ws + OFF_K);
  short* Vp    = (short*)(ws + OFF_VT);
  float* gates = (float*)(ws + OFF_GATE);
  int*   topi  = (int*)(ws + OFF_TOPI);
  float* aux   = (float*)(ws + OFF_AUX);
  short* allq  = (short*)(ws + OFF_ALLQ);
  short* mixed = (short*)(ws + OFF_ALLQ);  // alias: allq dead after attn q-gather
  float* out   = (float*)d_out;

  hipMemsetAsync(aux, 0, 256, stream);
  prep_kernel  <<<20736, 256, 0, stream>>>(x, W1, Wkv, W2, xb, Bt1, W2t);
  gating_kernel<<<1024, 256, 0, stream>>>(x, Wg, task, topi, gates, aux);
  aux_final    <<<1, 64, 0, stream>>>(aux, out + (size_t)TOK*DIM);
  // all_q (+ kv columns): [8192,768] x [768,2560]
  gemm_bt<true><<<dim3(NQP/128, TOK/128), 256, 0, stream>>>(xb, Bt1, allq, TOK, NQP, DIM);
  split_kv_tile<<<128, 256, 0, stream>>>(allq, bkv, Kp, Vp);
  attn_fwd     <<<dim3(16, 64), 256, 0, stream>>>(allq, topi, Kp, Vp, o);
  scatter_mixed<<<TOK, 256, 0, stream>>>(o, topi, gates, mixed);
  // out: [8192,2304] x [2304,768]
  gemm_bt_n64  <<<dim3(DIM/64, TOK/128), 256, 0, stream>>>(mixed, W2t, out, TOK, DIM, NQ);
}